// Round 2
// baseline (366.418 us; speedup 1.0000x reference)
//
#include <hip/hip_runtime.h>
#include <hip/hip_bf16.h>
#include <stdint.h>

#define USER_DIM 3706
#define ITEM_DIM 6040
#define LATENT   512
#define BATCH    8192
#define XCOLS    (USER_DIM + ITEM_DIM)   // 9746
#define KPAD_U   3712                     // 116*32  (even # of K-tiles)
#define KPAD_I   6080                     // 190*32  (even # of K-tiles)

typedef float f32x4 __attribute__((ext_vector_type(4)));
typedef short bf16x8 __attribute__((ext_vector_type(8)));

static __device__ __forceinline__ unsigned short f2bf(float f) {
    union { float f; unsigned int u; } v; v.f = f;
    unsigned int u = v.u;
    u += 0x7fffu + ((u >> 16) & 1u);   // RNE (finite inputs)
    return (unsigned short)(u >> 16);
}
static __device__ __forceinline__ float bf2f(unsigned int b) {
    union { unsigned int u; float f; } v; v.u = b << 16; return v.f;
}

// ---- Kernel 1: weight fp32 -> bf16, zero-padded K ----
__global__ void convert_w(const float* __restrict__ W, unsigned short* __restrict__ Wb,
                          int K, int Kpad) {
    int c = blockIdx.x * blockDim.x + threadIdx.x;
    int r = blockIdx.y;
    if (c >= Kpad) return;
    unsigned short o = 0;
    if (c < K) o = f2bf(W[(size_t)r * K + c]);
    Wb[(size_t)r * Kpad + c] = o;
}

// ---- Kernel 2: both towers fused.  Tile 64x128, BK=32, depth-2 pipeline. ----
// LDS layout: row-major [rows][32] bf16 (64B rows), 16B chunk swizzle c ^= (row&3).
struct Stage { float4 a0, a1; uint4 b0, b1; };

__global__ __launch_bounds__(256, 4) void gemm_fused(
    const float* __restrict__ X,
    const unsigned short* __restrict__ WuB, const float* __restrict__ bu,
    const unsigned short* __restrict__ WiB, const float* __restrict__ bi,
    unsigned short* __restrict__ Uemb, unsigned short* __restrict__ Iemb)
{
    __shared__ unsigned short sA[2][64 * 32];
    __shared__ unsigned short sB[2][128 * 32];

    const int tid  = threadIdx.x;
    const int lane = tid & 63;
    const int wid  = tid >> 6;
    const int wm   = wid >> 1;       // 0..1  (M half)
    const int wn   = wid & 1;        // 0..1  (N half)

    // XCD-chunked swizzle over 1024 blocks: each XCD gets one contiguous range
    // of (tower, mb) panels; 4 consecutive swz share mb (A-panel L2 reuse).
    const int bid = blockIdx.x;
    const int swz = (bid & 7) * 128 + (bid >> 3);
    const int tower = swz >> 9;          // 0 = user, 1 = item
    const int idx = swz & 511;
    const int mb = idx >> 2;             // 0..127
    const int nb = idx & 3;              // 0..3

    const float* Xb; const unsigned short* WB; const float* bias;
    unsigned short* Emb; int K, Kpad;
    if (tower == 0) { Xb = X;            WB = WuB; bias = bu; Emb = Uemb; K = USER_DIM; Kpad = KPAD_U; }
    else            { Xb = X + USER_DIM; WB = WiB; bias = bi; Emb = Iemb; K = ITEM_DIM; Kpad = KPAD_I; }

    // ---- staging maps: thread -> (row sr, 16B chunk sc) ----
    const int sr = tid >> 2;             // 0..63
    const int sc = tid & 3;              // 0..3
    const float*          xptr  = Xb + (size_t)(mb * 64 + sr) * XCOLS + sc * 8;
    const unsigned short* wptr0 = WB + (size_t)(nb * 128 + sr) * Kpad + sc * 8;
    const unsigned short* wptr1 = wptr0 + (size_t)64 * Kpad;
    const int swc  = ((sc ^ (sr & 3)) * 8);
    const int awo  = sr * 32 + swc;              // A LDS write elem offset
    const int bwo  = sr * 32 + swc;              // B row sr; row 64+sr at +2048

    // ---- fragment read bases ----
    const int fr = lane & 15;
    const int g  = lane >> 4;
    const int rc = ((g ^ (fr & 3)) * 8);
    const int aro = (wm * 32 + fr) * 32 + rc;    // + mi*512
    const int bro = (wn * 64 + fr) * 32 + rc;    // + ni*512

    f32x4 acc[2][4];
    #pragma unroll
    for (int i = 0; i < 2; ++i)
        #pragma unroll
        for (int j = 0; j < 4; ++j) acc[i][j] = (f32x4)0.0f;

    Stage rsA, rsB;

    auto stage_load = [&](Stage& s, int kt) {
        const int kbase = kt * 32;
        if (kbase + 32 <= K) {
            s.a0 = *(const float4*)(xptr + kbase);
            s.a1 = *(const float4*)(xptr + kbase + 4);
        } else {                                  // K tail (last tile only)
            float t[8];
            #pragma unroll
            for (int j = 0; j < 8; ++j) {
                int kg = kbase + sc * 8 + j;
                t[j] = (kg < K) ? xptr[kbase + j] : 0.0f;
            }
            s.a0 = make_float4(t[0], t[1], t[2], t[3]);
            s.a1 = make_float4(t[4], t[5], t[6], t[7]);
        }
        s.b0 = *(const uint4*)(wptr0 + kbase);    // B zero-padded to Kpad
        s.b1 = *(const uint4*)(wptr1 + kbase);
    };
    auto stage_write = [&](const Stage& s, int buf) {
        uint4 aw;
        aw.x = (unsigned int)f2bf(s.a0.x) | ((unsigned int)f2bf(s.a0.y) << 16);
        aw.y = (unsigned int)f2bf(s.a0.z) | ((unsigned int)f2bf(s.a0.w) << 16);
        aw.z = (unsigned int)f2bf(s.a1.x) | ((unsigned int)f2bf(s.a1.y) << 16);
        aw.w = (unsigned int)f2bf(s.a1.z) | ((unsigned int)f2bf(s.a1.w) << 16);
        *(uint4*)(&sA[buf][awo]) = aw;
        *(uint4*)(&sB[buf][bwo]) = s.b0;
        *(uint4*)(&sB[buf][bwo + 64 * 32]) = s.b1;
    };
    auto compute = [&](int buf) {
        bf16x8 af[2], bf[4];
        #pragma unroll
        for (int mi = 0; mi < 2; ++mi)
            af[mi] = *(const bf16x8*)(&sA[buf][aro + mi * 512]);
        #pragma unroll
        for (int ni = 0; ni < 4; ++ni)
            bf[ni] = *(const bf16x8*)(&sB[buf][bro + ni * 512]);
        #pragma unroll
        for (int mi = 0; mi < 2; ++mi)
            #pragma unroll
            for (int ni = 0; ni < 4; ++ni)
                acc[mi][ni] = __builtin_amdgcn_mfma_f32_16x16x32_bf16(
                    af[mi], bf[ni], acc[mi][ni], 0, 0, 0);
    };

    const int nt = Kpad / 32;                     // even (116 or 190)

    stage_load(rsA, 0);
    stage_load(rsB, 1);
    stage_write(rsA, 0);
    __syncthreads();

    for (int p = 0; p < nt; p += 2) {
        // even step: compute tile p from lds0; rsB holds tile p+1
        if (p + 2 < nt) stage_load(rsA, p + 2);
        compute(0);
        __syncthreads();
        stage_write(rsB, 1);                      // tile p+1 -> lds1
        __syncthreads();
        // odd step: compute tile p+1 from lds1; rsA holds tile p+2
        if (p + 3 < nt) stage_load(rsB, p + 3);
        compute(1);
        __syncthreads();
        if (p + 2 < nt) stage_write(rsA, 0);      // tile p+2 -> lds0
        __syncthreads();
    }

    // ---- epilogue: bias + relu + bf16 store ----
    const int cb = nb * 128 + wn * 64;
    const int rb = mb * 64 + wm * 32 + (lane >> 4) * 4;
    #pragma unroll
    for (int ni = 0; ni < 4; ++ni) {
        int col = cb + ni * 16 + fr;
        float bv = bias[col];
        #pragma unroll
        for (int mi = 0; mi < 2; ++mi) {
            f32x4 v = acc[mi][ni];
            #pragma unroll
            for (int r = 0; r < 4; ++r) {
                int row = rb + mi * 16 + r;
                Emb[(size_t)row * LATENT + col] = f2bf(fmaxf(v[r] + bv, 0.0f));
            }
        }
    }
}

// ---- Kernel 3: out[b] = sum_d U[b,d]*I[b,d] ----
__global__ void rowdot(const unsigned short* __restrict__ U,
                       const unsigned short* __restrict__ I,
                       float* __restrict__ out) {
    int lane = threadIdx.x & 63;
    int w = threadIdx.x >> 6;
    int row = blockIdx.x * 4 + w;
    const uint4 uv = *(const uint4*)(U + (size_t)row * LATENT + lane * 8);
    const uint4 iv = *(const uint4*)(I + (size_t)row * LATENT + lane * 8);
    const unsigned int* up = (const unsigned int*)&uv;
    const unsigned int* ip = (const unsigned int*)&iv;
    float acc = 0.0f;
    #pragma unroll
    for (int q = 0; q < 4; ++q) {
        acc += bf2f(up[q] & 0xffffu) * bf2f(ip[q] & 0xffffu);
        acc += bf2f(up[q] >> 16)     * bf2f(ip[q] >> 16);
    }
    #pragma unroll
    for (int off = 32; off >= 1; off >>= 1)
        acc += __shfl_xor(acc, off, 64);
    if (lane == 0) out[row] = acc;
}

extern "C" void kernel_launch(void* const* d_in, const int* in_sizes, int n_in,
                              void* d_out, int out_size, void* d_ws, size_t ws_size,
                              hipStream_t stream) {
    const float* x  = (const float*)d_in[0];
    const float* Wu = (const float*)d_in[1];
    const float* bu = (const float*)d_in[2];
    const float* Wi = (const float*)d_in[3];
    const float* bi = (const float*)d_in[4];
    float* out = (float*)d_out;

    unsigned short* WuB  = (unsigned short*)d_ws;                 // 512*3712
    unsigned short* WiB  = WuB + (size_t)LATENT * KPAD_U;         // 512*6080
    unsigned short* Uemb = WiB + (size_t)LATENT * KPAD_I;         // 8192*512
    unsigned short* Iemb = Uemb + (size_t)BATCH * LATENT;         // 8192*512

    convert_w<<<dim3((KPAD_U + 255) / 256, LATENT), 256, 0, stream>>>(Wu, WuB, USER_DIM, KPAD_U);
    convert_w<<<dim3((KPAD_I + 255) / 256, LATENT), 256, 0, stream>>>(Wi, WiB, ITEM_DIM, KPAD_I);

    gemm_fused<<<1024, 256, 0, stream>>>(x, WuB, bu, WiB, bi, Uemb, Iemb);

    rowdot<<<BATCH / 4, 256, 0, stream>>>(Uemb, Iemb, out);
}

// Round 3
// 326.818 us; speedup vs baseline: 1.1212x; 1.1212x over previous
//
#include <hip/hip_runtime.h>
#include <hip/hip_bf16.h>
#include <stdint.h>

#define USER_DIM 3706
#define ITEM_DIM 6040
#define LATENT   512
#define BATCH    8192
#define XCOLS    (USER_DIM + ITEM_DIM)   // 9746
#define KPAD_U   3712                     // 116*32  -> nt=116 (even)
#define KPAD_I   6080                     // 190*32  -> nt=190 (even)

typedef float f32x4 __attribute__((ext_vector_type(4)));
typedef short bf16x8 __attribute__((ext_vector_type(8)));

static __device__ __forceinline__ unsigned short f2bf(float f) {
    union { float f; unsigned int u; } v; v.f = f;
    unsigned int u = v.u;
    u += 0x7fffu + ((u >> 16) & 1u);   // RNE (finite inputs)
    return (unsigned short)(u >> 16);
}
static __device__ __forceinline__ float bf2f(unsigned int b) {
    union { unsigned int u; float f; } v; v.u = b << 16; return v.f;
}
static __device__ __forceinline__ short cvt1(float f) {
    union { __hip_bfloat16 h; unsigned short u; } cv;
    cv.h = __float2bfloat16(f);                 // RNE; compiler can pair into v_cvt_pk_bf16_f32
    return (short)cv.u;
}
static __device__ __forceinline__ bf16x8 cvt8(f32x4 lo, f32x4 hi) {
    bf16x8 r;
    #pragma unroll
    for (int i = 0; i < 4; ++i) { r[i] = cvt1(lo[i]); r[4 + i] = cvt1(hi[i]); }
    return r;
}
static __device__ __forceinline__ void gload16(const void* g, void* l) {
    __builtin_amdgcn_global_load_lds(
        (const __attribute__((address_space(1))) void*)g,
        (__attribute__((address_space(3))) void*)l, 16, 0, 0);
}

// ---- Kernel 1: weight fp32 -> bf16, zero-padded K ----
__global__ void convert_w(const float* __restrict__ W, unsigned short* __restrict__ Wb,
                          int K, int Kpad) {
    int c = blockIdx.x * blockDim.x + threadIdx.x;
    int r = blockIdx.y;
    if (c >= Kpad) return;
    unsigned short o = 0;
    if (c < K) o = f2bf(W[(size_t)r * K + c]);
    Wb[(size_t)r * Kpad + c] = o;
}

// ---- Kernel 2: fused towers, m97 structure.
// Tile 128x128, BK=32, 4 waves (2x2), per-wave 64x64 (4x4 frags), global_load_lds staging.
// LDS A: fp32 [128 rows][8 chunks of 16B], chunk swizzle c' = c ^ (row&7), linear dest.
// LDS B: bf16 [128 rows][4 chunks of 16B], chunk swizzle c' = c ^ ((row>>1)&3), linear dest.
// Swizzle applied on the per-lane GLOBAL source + on the ds_read side (rule #21).
__global__ __launch_bounds__(256, 2) void gemm_fused(
    const float* __restrict__ X,
    const unsigned short* __restrict__ WuB, const float* __restrict__ bu,
    const unsigned short* __restrict__ WiB, const float* __restrict__ bi,
    unsigned short* __restrict__ Uemb, unsigned short* __restrict__ Iemb)
{
    __shared__ float          sA2[2][128 * 32];   // 2 x 16 KB
    __shared__ unsigned short sB2[2][128 * 32];   // 2 x  8 KB

    const int tid  = threadIdx.x;
    const int lane = tid & 63;
    const int wid  = tid >> 6;
    const int wm   = wid >> 1;
    const int wn   = wid & 1;

    // bijective XCD-chunk swizzle (512 = 8*64); towers interleaved within each XCD.
    const int bid = blockIdx.x;
    const int swz = (bid & 7) * 64 + (bid >> 3);
    const int nb    = swz & 3;          // 0..3   (N tile)
    const int tower = (swz >> 2) & 1;   // alternate towers in groups of 4 (A-panel sharers)
    const int mb    = swz >> 3;         // 0..63  (M tile)

    const float* Xb; const unsigned short* WB; const float* bias;
    unsigned short* Emb; int K, Kpad;
    if (tower == 0) { Xb = X;            WB = WuB; bias = bu; Emb = Uemb; K = USER_DIM; Kpad = KPAD_U; }
    else            { Xb = X + USER_DIM; WB = WiB; bias = bi; Emb = Iemb; K = ITEM_DIM; Kpad = KPAD_I; }
    const int nt = Kpad / 32;

    // ---- staging geometry (per-lane global addresses, wave-uniform LDS bases) ----
    // A: 16 issues of 1KB (8 rows x 128B); issue i -> rows i*8..i*8+7. 4 issues/wave.
    const int a_row_in = lane >> 3;                       // 0..7 within issue
    const int a_cs     = (lane & 7) ^ a_row_in;           // global 16B-chunk (= (l&7)^(row&7))
    // B: 8 issues of 1KB (16 rows x 64B); issue i -> rows i*16..i*16+15. 2 issues/wave.
    const int b_row_in = lane >> 2;                       // 0..15 within issue
    const int b_cs     = (lane & 3) ^ ((lane >> 3) & 3);  // = (l&3)^((row>>1)&3)

    // ---- fragment read geometry ----
    const int fr = lane & 15;
    const int g  = lane >> 4;            // 0..3
    const int sA_swz = lane & 7;         // row&7 for A frag rows
    const int b_rswz = (fr >> 1) & 3;

    f32x4 acc[4][4];
    #pragma unroll
    for (int i = 0; i < 4; ++i)
        #pragma unroll
        for (int j = 0; j < 4; ++j) acc[i][j] = (f32x4)0.0f;

    auto STAGE = [&](int buf, int t) {
        const int kbase = t * 32;
        const bool tail = (kbase + 32 > K);
        float*          sA = sA2[buf];
        unsigned short* sB = sB2[buf];
        #pragma unroll
        for (int j = 0; j < 4; ++j) {
            const int i   = wid * 4 + j;                  // 0..15
            const int row = i * 8 + a_row_in;
            const int kc  = kbase + a_cs * 4;
            const float* gsrc = Xb + (size_t)(mb * 128 + row) * XCOLS + kc;
            if (tail && kc >= K) gsrc = Xb;               // safe dummy; hits B zero-pad
            gload16(gsrc, sA + i * 256);                  // 1KB per issue, linear dest
        }
        #pragma unroll
        for (int j = 0; j < 2; ++j) {
            const int i   = wid * 2 + j;                  // 0..7
            const int row = i * 16 + b_row_in;
            const unsigned short* gsrc = WB + (size_t)(nb * 128 + row) * Kpad + kbase + b_cs * 8;
            gload16(gsrc, sB + i * 512);
        }
    };

    auto COMPUTE = [&](int buf) {
        const float*          sA = sA2[buf];
        const unsigned short* sB = sB2[buf];
        bf16x8 af[4], bfr[4];
        #pragma unroll
        for (int mi = 0; mi < 4; ++mi) {
            const int r = wm * 64 + mi * 16 + fr;
            const float* base = sA + r * 32;
            f32x4 lo = *(const f32x4*)(base + (((2 * g)     ^ sA_swz) * 4));
            f32x4 hi = *(const f32x4*)(base + (((2 * g + 1) ^ sA_swz) * 4));
            af[mi] = cvt8(lo, hi);
        }
        #pragma unroll
        for (int ni = 0; ni < 4; ++ni) {
            const int r = wn * 64 + ni * 16 + fr;
            bfr[ni] = *(const bf16x8*)(sB + r * 32 + ((g ^ b_rswz) * 8));
        }
        #pragma unroll
        for (int mi = 0; mi < 4; ++mi)
            #pragma unroll
            for (int ni = 0; ni < 4; ++ni)
                acc[mi][ni] = __builtin_amdgcn_mfma_f32_16x16x32_bf16(
                    af[mi], bfr[ni], acc[mi][ni], 0, 0, 0);
    };

    STAGE(0, 0);
    __syncthreads();
    for (int t = 0; t < nt; t += 2) {          // nt is even (116 / 190)
        STAGE(1, t + 1);
        COMPUTE(0);
        __syncthreads();
        if (t + 2 < nt) STAGE(0, t + 2);
        COMPUTE(1);
        __syncthreads();
    }

    // ---- epilogue: bias + relu + bf16 store ----
    const int cb = nb * 128 + wn * 64;
    const int rb = mb * 128 + wm * 64 + (lane >> 4) * 4;
    #pragma unroll
    for (int ni = 0; ni < 4; ++ni) {
        const int col = cb + ni * 16 + fr;
        const float bv = bias[col];
        #pragma unroll
        for (int mi = 0; mi < 4; ++mi) {
            f32x4 v = acc[mi][ni];
            #pragma unroll
            for (int r = 0; r < 4; ++r) {
                const int row = rb + mi * 16 + r;
                Emb[(size_t)row * LATENT + col] = f2bf(fmaxf(v[r] + bv, 0.0f));
            }
        }
    }
}

// ---- Kernel 3: out[b] = sum_d U[b,d]*I[b,d] ----
__global__ void rowdot(const unsigned short* __restrict__ U,
                       const unsigned short* __restrict__ I,
                       float* __restrict__ out) {
    int lane = threadIdx.x & 63;
    int w = threadIdx.x >> 6;
    int row = blockIdx.x * 4 + w;
    const uint4 uv = *(const uint4*)(U + (size_t)row * LATENT + lane * 8);
    const uint4 iv = *(const uint4*)(I + (size_t)row * LATENT + lane * 8);
    const unsigned int* up = (const unsigned int*)&uv;
    const unsigned int* ip = (const unsigned int*)&iv;
    float acc = 0.0f;
    #pragma unroll
    for (int q = 0; q < 4; ++q) {
        acc += bf2f(up[q] & 0xffffu) * bf2f(ip[q] & 0xffffu);
        acc += bf2f(up[q] >> 16)     * bf2f(ip[q] >> 16);
    }
    #pragma unroll
    for (int off = 32; off >= 1; off >>= 1)
        acc += __shfl_xor(acc, off, 64);
    if (lane == 0) out[row] = acc;
}

extern "C" void kernel_launch(void* const* d_in, const int* in_sizes, int n_in,
                              void* d_out, int out_size, void* d_ws, size_t ws_size,
                              hipStream_t stream) {
    const float* x  = (const float*)d_in[0];
    const float* Wu = (const float*)d_in[1];
    const float* bu = (const float*)d_in[2];
    const float* Wi = (const float*)d_in[3];
    const float* bi = (const float*)d_in[4];
    float* out = (float*)d_out;

    unsigned short* WuB  = (unsigned short*)d_ws;                 // 512*3712 bf16
    unsigned short* WiB  = WuB + (size_t)LATENT * KPAD_U;         // 512*6080 bf16
    unsigned short* Uemb = WiB + (size_t)LATENT * KPAD_I;         // 8192*512 bf16
    unsigned short* Iemb = Uemb + (size_t)BATCH * LATENT;         // 8192*512 bf16

    convert_w<<<dim3((KPAD_U + 255) / 256, LATENT), 256, 0, stream>>>(Wu, WuB, USER_DIM, KPAD_U);
    convert_w<<<dim3((KPAD_I + 255) / 256, LATENT), 256, 0, stream>>>(Wi, WiB, ITEM_DIM, KPAD_I);

    gemm_fused<<<512, 256, 0, stream>>>(x, WuB, bu, WiB, bi, Uemb, Iemb);

    rowdot<<<BATCH / 4, 256, 0, stream>>>(Uemb, Iemb, out);
}

// Round 4
// 295.912 us; speedup vs baseline: 1.2383x; 1.1044x over previous
//
#include <hip/hip_runtime.h>
#include <hip/hip_bf16.h>
#include <stdint.h>

#define USER_DIM 3706
#define ITEM_DIM 6040
#define LATENT   512
#define BATCH    8192
#define XCOLS    (USER_DIM + ITEM_DIM)   // 9746
#define KPAD_U   3712                     // 58 * 64
#define KPAD_I   6144                     // 96 * 64  (two halves of 48 steps)

typedef float f32x4 __attribute__((ext_vector_type(4)));
typedef short bf16x8 __attribute__((ext_vector_type(8)));

static __device__ __forceinline__ unsigned short f2bf(float f) {
    union { float f; unsigned int u; } v; v.f = f;
    unsigned int u = v.u;
    u += 0x7fffu + ((u >> 16) & 1u);   // RNE (finite inputs)
    return (unsigned short)(u >> 16);
}
static __device__ __forceinline__ float bf2f(unsigned int b) {
    union { unsigned int u; float f; } v; v.u = b << 16; return v.f;
}
static __device__ __forceinline__ void gload16(const void* g, void* l) {
    __builtin_amdgcn_global_load_lds(
        (const __attribute__((address_space(1))) void*)g,
        (__attribute__((address_space(3))) void*)l, 16, 0, 0);
}

// ---- Kernel 1: weight fp32 -> bf16, zero-padded K ----
__global__ void convert_w(const float* __restrict__ W, unsigned short* __restrict__ Wb,
                          int K, int Kpad) {
    int c = blockIdx.x * blockDim.x + threadIdx.x;
    int r = blockIdx.y;
    if (c >= Kpad) return;
    unsigned short o = 0;
    if (c < K) o = f2bf(W[(size_t)r * K + c]);
    Wb[(size_t)r * Kpad + c] = o;
}

// ---- Kernel 2: fused towers. Tile 128x128, BK=64, 4 waves, one barrier/K-step.
// A: global fp32 -> regs -> (cvt) -> LDS bf16 [128][64], 16B-chunk swizzle c^=(row&7).
// B: global_load_lds direct, LDS linear dest, swizzle pre-applied on global source.
// Item tower split into two K-halves (48 steps each) writing bf16 partials.
__global__ __launch_bounds__(256, 2) void gemm_fused(
    const float* __restrict__ X,
    const unsigned short* __restrict__ WuB, const float* __restrict__ bu,
    const unsigned short* __restrict__ WiB,
    unsigned short* __restrict__ Uemb,
    unsigned short* __restrict__ P0, unsigned short* __restrict__ P1)
{
    __shared__ unsigned short sA2[2][128 * 64];   // 2 x 16 KB bf16
    __shared__ unsigned short sB2[2][128 * 64];   // 2 x 16 KB bf16

    const int tid  = threadIdx.x;
    const int lane = tid & 63;
    const int wid  = tid >> 6;
    const int wm   = wid >> 1;
    const int wn   = wid & 1;

    // XCD-chunked bijective swizzle over 768 blocks (= 8 * 96).
    const int bid = blockIdx.x;
    const int swz = (bid & 7) * 96 + (bid >> 3);

    int mb, nb, k0, nt, xoff, Kpad;
    const unsigned short* WB;
    bool isUser;
    int kh = 0;
    if (swz < 256) {                 // user tower: 64 mb x 4 nb
        isUser = true;  mb = swz >> 2; nb = swz & 3;
        k0 = 0; nt = KPAD_U / 64; xoff = 0; Kpad = KPAD_U; WB = WuB;
    } else {                         // item tower: 64 mb x 4 nb x 2 kh
        const int q = swz - 256;
        isUser = false; mb = q >> 3; nb = (q >> 1) & 3; kh = q & 1;
        k0 = kh * 48; nt = 48; xoff = USER_DIM; Kpad = KPAD_I; WB = WiB;
    }

    // ---- A staging: load j -> row wid*32 + j*4 + (lane>>4), 16 lanes x 16B contiguous ----
    const int a_r = lane >> 4;            // 0..3
    const int a_c = (lane & 15) * 4;      // fp32 col within BK
    const int w_c = (lane & 15) >> 1;     // 16B bf16 chunk 0..7
    const int w_h = lane & 1;             // low/high 8B half
    // ---- B staging (gload_lds, pre-swizzled global source) ----
    const int b_rl = lane >> 3;           // 0..7 (row within 8-row issue)
    const int b_cs = (lane & 7) ^ b_rl;   // global 16B chunk

    float4 ar[8];

    auto ISSUE_A = [&](int t) {
        const int kb = t * 64;
        #pragma unroll
        for (int j = 0; j < 8; ++j) {
            const int row = mb * 128 + wid * 32 + j * 4 + a_r;
            const int xc  = xoff + kb + a_c;
            const float* s = X + (size_t)row * XCOLS + xc;
            if (xc + 4 > XCOLS) s = X;    // item tail (k>=6040): B is zero there
            ar[j] = *(const float4*)s;
        }
    };
    auto WRITE_A = [&](int buf) {
        unsigned short* sA = sA2[buf];
        #pragma unroll
        for (int j = 0; j < 8; ++j) {
            const int rl = wid * 32 + j * 4 + a_r;
            uint2 p;
            p.x = (unsigned)f2bf(ar[j].x) | ((unsigned)f2bf(ar[j].y) << 16);
            p.y = (unsigned)f2bf(ar[j].z) | ((unsigned)f2bf(ar[j].w) << 16);
            *(uint2*)(sA + rl * 64 + ((w_c ^ (rl & 7)) * 8 + w_h * 4)) = p;
        }
    };
    auto ISSUE_B = [&](int t, int buf) {
        const int kb = t * 64;
        unsigned short* sB = sB2[buf];
        #pragma unroll
        for (int j = 0; j < 4; ++j) {
            const int i   = wid * 4 + j;               // 0..15 (8 rows each)
            const int row = i * 8 + b_rl;
            const unsigned short* g =
                WB + (size_t)(nb * 128 + row) * Kpad + kb + b_cs * 8;
            gload16(g, sB + i * 512);                  // linear dest (rule #21)
        }
    };

    // ---- fragment geometry ----
    const int fr = lane & 15;
    const int g  = lane >> 4;

    f32x4 acc[4][4];
    #pragma unroll
    for (int i = 0; i < 4; ++i)
        #pragma unroll
        for (int j = 0; j < 4; ++j) acc[i][j] = (f32x4)0.0f;

    auto COMPUTE = [&](int buf) {
        const unsigned short* sA = sA2[buf];
        const unsigned short* sB = sB2[buf];
        bf16x8 af[2][4], bfr[2][4];
        #pragma unroll
        for (int mi = 0; mi < 4; ++mi) {
            const int r = wm * 64 + mi * 16 + fr;
            #pragma unroll
            for (int ks = 0; ks < 2; ++ks)
                af[ks][mi] = *(const bf16x8*)(sA + r * 64 + (((ks * 4 + g) ^ (r & 7)) * 8));
        }
        #pragma unroll
        for (int ni = 0; ni < 4; ++ni) {
            const int r = wn * 64 + ni * 16 + fr;
            #pragma unroll
            for (int ks = 0; ks < 2; ++ks)
                bfr[ks][ni] = *(const bf16x8*)(sB + r * 64 + (((ks * 4 + g) ^ (r & 7)) * 8));
        }
        #pragma unroll
        for (int ks = 0; ks < 2; ++ks)
            #pragma unroll
            for (int mi = 0; mi < 4; ++mi)
                #pragma unroll
                for (int ni = 0; ni < 4; ++ni)
                    acc[mi][ni] = __builtin_amdgcn_mfma_f32_16x16x32_bf16(
                        af[ks][mi], bfr[ks][ni], acc[mi][ni], 0, 0, 0);
    };

    // ---- pipeline: one barrier per K-step; loads get a full compute phase in flight ----
    ISSUE_A(k0); ISSUE_B(k0, 0);
    WRITE_A(0);                          // compiler waits A(k0) regs
    __syncthreads();                     // drains B(k0)
    ISSUE_A(k0 + 1); ISSUE_B(k0 + 1, 1);

    for (int tt = 0; tt < nt; tt += 2) { // nt even (58 or 48)
        const bool more = (tt + 2 < nt);
        COMPUTE(0);                      // tile tt
        WRITE_A(1);                      // A(tt+1): regs (one phase old) -> LDS1
        __syncthreads();                 // drains B(tt+1)
        if (more) { ISSUE_A(k0 + tt + 2); ISSUE_B(k0 + tt + 2, 0); }
        COMPUTE(1);                      // tile tt+1
        if (more) {
            WRITE_A(0);                  // A(tt+2)
            __syncthreads();             // drains B(tt+2)
            ISSUE_A(k0 + tt + 3); ISSUE_B(k0 + tt + 3, 1);
        }
    }

    // ---- epilogue ----
    const int cb = nb * 128 + wn * 64;
    const int rb = mb * 128 + wm * 64 + (lane >> 4) * 4;
    if (isUser) {
        #pragma unroll
        for (int ni = 0; ni < 4; ++ni) {
            const int col = cb + ni * 16 + fr;
            const float bv = bu[col];
            #pragma unroll
            for (int mi = 0; mi < 4; ++mi) {
                f32x4 v = acc[mi][ni];
                #pragma unroll
                for (int r = 0; r < 4; ++r) {
                    const int row = rb + mi * 16 + r;
                    Uemb[(size_t)row * LATENT + col] = f2bf(fmaxf(v[r] + bv, 0.0f));
                }
            }
        }
    } else {
        unsigned short* P = kh ? P1 : P0;
        #pragma unroll
        for (int ni = 0; ni < 4; ++ni) {
            const int col = cb + ni * 16 + fr;
            #pragma unroll
            for (int mi = 0; mi < 4; ++mi) {
                f32x4 v = acc[mi][ni];
                #pragma unroll
                for (int r = 0; r < 4; ++r) {
                    const int row = rb + mi * 16 + r;
                    P[(size_t)row * LATENT + col] = f2bf(v[r]);   // partial, no bias/relu
                }
            }
        }
    }
}

// ---- Kernel 3: out[b] = sum_d U[b,d] * relu(P0[b,d] + P1[b,d] + bi[d]) ----
__global__ void rowdot(const unsigned short* __restrict__ U,
                       const unsigned short* __restrict__ P0,
                       const unsigned short* __restrict__ P1,
                       const float* __restrict__ bi,
                       float* __restrict__ out) {
    const int lane = threadIdx.x & 63;
    const int w    = threadIdx.x >> 6;
    const int row  = blockIdx.x * 4 + w;
    const size_t base = (size_t)row * LATENT + lane * 8;
    const uint4 uv = *(const uint4*)(U  + base);
    const uint4 p0 = *(const uint4*)(P0 + base);
    const uint4 p1 = *(const uint4*)(P1 + base);
    const float4 b0 = *(const float4*)(bi + lane * 8);
    const float4 b1 = *(const float4*)(bi + lane * 8 + 4);
    const float bb[8] = {b0.x, b0.y, b0.z, b0.w, b1.x, b1.y, b1.z, b1.w};
    const unsigned int* up  = (const unsigned int*)&uv;
    const unsigned int* q0  = (const unsigned int*)&p0;
    const unsigned int* q1  = (const unsigned int*)&p1;
    float acc = 0.0f;
    #pragma unroll
    for (int q = 0; q < 4; ++q) {
        float ilo = fmaxf(bf2f(q0[q] & 0xffffu) + bf2f(q1[q] & 0xffffu) + bb[2 * q], 0.0f);
        float ihi = fmaxf(bf2f(q0[q] >> 16)     + bf2f(q1[q] >> 16)     + bb[2 * q + 1], 0.0f);
        acc += bf2f(up[q] & 0xffffu) * ilo;
        acc += bf2f(up[q] >> 16)     * ihi;
    }
    #pragma unroll
    for (int off = 32; off >= 1; off >>= 1)
        acc += __shfl_xor(acc, off, 64);
    if (lane == 0) out[row] = acc;
}

extern "C" void kernel_launch(void* const* d_in, const int* in_sizes, int n_in,
                              void* d_out, int out_size, void* d_ws, size_t ws_size,
                              hipStream_t stream) {
    const float* x  = (const float*)d_in[0];
    const float* Wu = (const float*)d_in[1];
    const float* bu = (const float*)d_in[2];
    const float* Wi = (const float*)d_in[3];
    const float* bi = (const float*)d_in[4];
    float* out = (float*)d_out;

    unsigned short* WuB  = (unsigned short*)d_ws;                 // 512*3712 bf16
    unsigned short* WiB  = WuB + (size_t)LATENT * KPAD_U;         // 512*6144 bf16
    unsigned short* Uemb = WiB + (size_t)LATENT * KPAD_I;         // 8192*512 bf16
    unsigned short* P0   = Uemb + (size_t)BATCH * LATENT;         // 8192*512 bf16
    unsigned short* P1   = P0   + (size_t)BATCH * LATENT;         // 8192*512 bf16

    convert_w<<<dim3((KPAD_U + 255) / 256, LATENT), 256, 0, stream>>>(Wu, WuB, USER_DIM, KPAD_U);
    convert_w<<<dim3((KPAD_I + 255) / 256, LATENT), 256, 0, stream>>>(Wi, WiB, ITEM_DIM, KPAD_I);

    // 256 user blocks (58 steps) + 512 item half-K blocks (48 steps) = 768
    gemm_fused<<<768, 256, 0, stream>>>(x, WuB, bu, WiB, Uemb, P0, P1);

    rowdot<<<BATCH / 4, 256, 0, stream>>>(Uemb, P0, P1, bi, out);
}

// Round 5
// 237.134 us; speedup vs baseline: 1.5452x; 1.2479x over previous
//
#include <hip/hip_runtime.h>
#include <hip/hip_bf16.h>
#include <stdint.h>

#define USER_DIM 3706
#define ITEM_DIM 6040
#define LATENT   512
#define BATCH    8192
#define XCOLS    (USER_DIM + ITEM_DIM)   // 9746
#define KPAD_U   3712                     // 116 * 32
#define KPAD_I   6144                     // 192 * 32 (two halves of 96 steps)

typedef float f32x4 __attribute__((ext_vector_type(4)));
typedef short bf16x8 __attribute__((ext_vector_type(8)));

#define VMCNT(n) asm volatile("s_waitcnt vmcnt(" #n ")" ::: "memory")

static __device__ __forceinline__ unsigned short f2bf(float f) {
    union { float f; unsigned int u; } v; v.f = f;
    unsigned int u = v.u;
    u += 0x7fffu + ((u >> 16) & 1u);   // RNE (finite inputs)
    return (unsigned short)(u >> 16);
}
static __device__ __forceinline__ float bf2f(unsigned int b) {
    union { unsigned int u; float f; } v; v.u = b << 16; return v.f;
}
static __device__ __forceinline__ short cvt1(float f) {
    union { __hip_bfloat16 h; unsigned short u; } cv;
    cv.h = __float2bfloat16(f);
    return (short)cv.u;
}
static __device__ __forceinline__ bf16x8 cvt8(f32x4 lo, f32x4 hi) {
    bf16x8 r;
    #pragma unroll
    for (int i = 0; i < 4; ++i) { r[i] = cvt1(lo[i]); r[4 + i] = cvt1(hi[i]); }
    return r;
}
static __device__ __forceinline__ void gload16(const void* g, void* l) {
    __builtin_amdgcn_global_load_lds(
        (const __attribute__((address_space(1))) void*)g,
        (__attribute__((address_space(3))) void*)l, 16, 0, 0);
}
static __device__ __forceinline__ void BARRIER() {
    __builtin_amdgcn_sched_barrier(0);
    __builtin_amdgcn_s_barrier();
    __builtin_amdgcn_sched_barrier(0);
}

// ---- Kernel 1: weight fp32 -> bf16, zero-padded K ----
__global__ void convert_w(const float* __restrict__ W, unsigned short* __restrict__ Wb,
                          int K, int Kpad) {
    int c = blockIdx.x * blockDim.x + threadIdx.x;
    int r = blockIdx.y;
    if (c >= Kpad) return;
    unsigned short o = 0;
    if (c < K) o = f2bf(W[(size_t)r * K + c]);
    Wb[(size_t)r * Kpad + c] = o;
}

// ---- Kernel 2: fused towers, 128x128 tile, BK=32, all-gload_lds staging,
//      counted-vmcnt raw-barrier pipeline (loads never drained mid-loop).
// LDS A: fp32 [128 rows][8 x 16B chunks], content chunk c_l = global (c_l ^ (r&7)).
// LDS B: bf16, rows packed 2/128B segment: LDS[seg][c8], c8 = ((r&1)*4+c) ^ (seg&7).
__global__ __launch_bounds__(256, 3) void gemm_fused(
    const float* __restrict__ X,
    const unsigned short* __restrict__ WuB, const float* __restrict__ bu,
    const unsigned short* __restrict__ WiB,
    unsigned short* __restrict__ Uemb,
    unsigned short* __restrict__ P0, unsigned short* __restrict__ P1)
{
    __shared__ float          sA2[2][128 * 32];   // 2 x 16 KB fp32
    __shared__ unsigned short sB2[2][128 * 32];   // 2 x  8 KB bf16

    const int tid  = threadIdx.x;
    const int lane = tid & 63;
    const int wid  = tid >> 6;
    const int wm   = wid >> 1;
    const int wn   = wid & 1;

    // XCD-chunked bijective swizzle over 768 blocks (= 8 * 96).
    const int bid = blockIdx.x;
    const int swz = (bid & 7) * 96 + (bid >> 3);
    const int g4  = swz >> 2;          // group 0..191 (4 nb each)
    const int nb  = swz & 3;

    // balanced tower interleave: 1 user : 2 item within every XCD
    int mb, k0, nt, xoff, Kpad;
    const unsigned short* WB;
    bool isUser; int kh = 0;
    if (g4 % 3 == 0) {
        isUser = true;  mb = g4 / 3;
        k0 = 0; nt = KPAD_U / 32; xoff = 0; Kpad = KPAD_U; WB = WuB;
    } else {
        const int q = g4 - (g4 / 3 + 1);     // 0..127 bijective
        isUser = false; mb = q >> 1; kh = q & 1;
        k0 = kh * 96; nt = 96; xoff = USER_DIM; Kpad = KPAD_I; WB = WiB;
    }

    // ---- staging lane geometry ----
    const int a_ri = lane >> 3;                 // A: row within 8-row issue
    const int a_cs = (lane & 7) ^ a_ri;         // A: global 16B chunk (fp32 x4)
    const int b_si = lane >> 3;                 // B: segment within issue
    const int b_c8 = (lane & 7) ^ b_si;         // B: global within-seg chunk
    const int b_rr = b_c8 >> 2;                 // B: row parity
    const int b_cc = b_c8 & 3;                  // B: global chunk (8 bf16)

    auto ISSUE = [&](int t, int buf) {
        const int kb = t * 32;
        float*          sA = sA2[buf];
        unsigned short* sB = sB2[buf];
        #pragma unroll
        for (int j = 0; j < 4; ++j) {
            const int i   = wid * 4 + j;                    // 0..15
            const int row = mb * 128 + i * 8 + a_ri;
            const int xc  = xoff + kb + a_cs * 4;
            const float* s = X + (size_t)row * XCOLS + xc;
            if (xc + 4 > XCOLS) s = X;                      // OOB guard (hits zero-B)
            gload16(s, sA + i * 256);
        }
        #pragma unroll
        for (int j = 0; j < 2; ++j) {
            const int i  = wid * 2 + j;                     // 0..7
            const int rt = (i * 8 + b_si) * 2 + b_rr;       // tile row 0..127
            const unsigned short* s =
                WB + (size_t)(nb * 128 + rt) * Kpad + kb + b_cc * 8;
            gload16(s, sB + i * 512);
        }
    };

    // ---- fragment geometry ----
    const int fr = lane & 15;
    const int g  = lane >> 4;

    f32x4 acc[4][4];
    #pragma unroll
    for (int i = 0; i < 4; ++i)
        #pragma unroll
        for (int j = 0; j < 4; ++j) acc[i][j] = (f32x4)0.0f;

    auto COMPUTE = [&](int buf) {
        const float*          sA = sA2[buf];
        const unsigned short* sB = sB2[buf];
        bf16x8 af[4], bfr[4];
        #pragma unroll
        for (int mi = 0; mi < 4; ++mi) {
            const int r = wm * 64 + mi * 16 + fr;
            const float* base = sA + r * 32;
            const int s = r & 7;
            f32x4 lo = *(const f32x4*)(base + (((2 * g)     ^ s) * 4));
            f32x4 hi = *(const f32x4*)(base + (((2 * g + 1) ^ s) * 4));
            af[mi] = cvt8(lo, hi);
        }
        #pragma unroll
        for (int ni = 0; ni < 4; ++ni) {
            const int r   = wn * 64 + ni * 16 + fr;
            const int seg = r >> 1;
            const int c8  = ((r & 1) * 4 + g) ^ (seg & 7);
            bfr[ni] = *(const bf16x8*)(sB + seg * 64 + c8 * 8);
        }
        #pragma unroll
        for (int mi = 0; mi < 4; ++mi)
            #pragma unroll
            for (int ni = 0; ni < 4; ++ni)
                acc[mi][ni] = __builtin_amdgcn_mfma_f32_16x16x32_bf16(
                    af[mi], bfr[ni], acc[mi][ni], 0, 0, 0);
    };

    // ---- counted-vmcnt pipeline: 6 loads/wave/tile; never drain mid-loop ----
    ISSUE(k0, 0);
    VMCNT(0);
    BARRIER();                       // tile 0 ready
    ISSUE(k0 + 1, 1);                // 6 in flight

    for (int t = 0; t < nt; ++t) {
        COMPUTE(t & 1);
        BARRIER();                   // all waves done reading buf
        if (t + 2 < nt) {
            ISSUE(k0 + t + 2, t & 1);
            VMCNT(6);                // tile t+1's 6 loads landed; t+2's stay in flight
        } else {
            VMCNT(0);                // tail: drain remaining
        }
        BARRIER();                   // buf^1 (tile t+1) visible to all waves
    }

    // ---- epilogue ----
    const int cb = nb * 128 + wn * 64;
    const int rb = mb * 128 + wm * 64 + (lane >> 4) * 4;
    if (isUser) {
        #pragma unroll
        for (int ni = 0; ni < 4; ++ni) {
            const int col = cb + ni * 16 + fr;
            const float bv = bu[col];
            #pragma unroll
            for (int mi = 0; mi < 4; ++mi) {
                f32x4 v = acc[mi][ni];
                #pragma unroll
                for (int r = 0; r < 4; ++r) {
                    const int row = rb + mi * 16 + r;
                    Uemb[(size_t)row * LATENT + col] = f2bf(fmaxf(v[r] + bv, 0.0f));
                }
            }
        }
    } else {
        unsigned short* P = kh ? P1 : P0;
        #pragma unroll
        for (int ni = 0; ni < 4; ++ni) {
            const int col = cb + ni * 16 + fr;
            #pragma unroll
            for (int mi = 0; mi < 4; ++mi) {
                f32x4 v = acc[mi][ni];
                #pragma unroll
                for (int r = 0; r < 4; ++r) {
                    const int row = rb + mi * 16 + r;
                    P[(size_t)row * LATENT + col] = f2bf(v[r]);   // partial
                }
            }
        }
    }
}

// ---- Kernel 3: out[b] = sum_d U[b,d] * relu(P0[b,d] + P1[b,d] + bi[d]) ----
__global__ void rowdot(const unsigned short* __restrict__ U,
                       const unsigned short* __restrict__ P0,
                       const unsigned short* __restrict__ P1,
                       const float* __restrict__ bi,
                       float* __restrict__ out) {
    const int lane = threadIdx.x & 63;
    const int w    = threadIdx.x >> 6;
    const int row  = blockIdx.x * 4 + w;
    const size_t base = (size_t)row * LATENT + lane * 8;
    const uint4 uv = *(const uint4*)(U  + base);
    const uint4 p0 = *(const uint4*)(P0 + base);
    const uint4 p1 = *(const uint4*)(P1 + base);
    const float4 b0 = *(const float4*)(bi + lane * 8);
    const float4 b1 = *(const float4*)(bi + lane * 8 + 4);
    const float bb[8] = {b0.x, b0.y, b0.z, b0.w, b1.x, b1.y, b1.z, b1.w};
    const unsigned int* up = (const unsigned int*)&uv;
    const unsigned int* q0 = (const unsigned int*)&p0;
    const unsigned int* q1 = (const unsigned int*)&p1;
    float acc = 0.0f;
    #pragma unroll
    for (int q = 0; q < 4; ++q) {
        float ilo = fmaxf(bf2f(q0[q] & 0xffffu) + bf2f(q1[q] & 0xffffu) + bb[2 * q], 0.0f);
        float ihi = fmaxf(bf2f(q0[q] >> 16)     + bf2f(q1[q] >> 16)     + bb[2 * q + 1], 0.0f);
        acc += bf2f(up[q] & 0xffffu) * ilo;
        acc += bf2f(up[q] >> 16)     * ihi;
    }
    #pragma unroll
    for (int off = 32; off >= 1; off >>= 1)
        acc += __shfl_xor(acc, off, 64);
    if (lane == 0) out[row] = acc;
}

extern "C" void kernel_launch(void* const* d_in, const int* in_sizes, int n_in,
                              void* d_out, int out_size, void* d_ws, size_t ws_size,
                              hipStream_t stream) {
    const float* x  = (const float*)d_in[0];
    const float* Wu = (const float*)d_in[1];
    const float* bu = (const float*)d_in[2];
    const float* Wi = (const float*)d_in[3];
    const float* bi = (const float*)d_in[4];
    float* out = (float*)d_out;

    unsigned short* WuB  = (unsigned short*)d_ws;                 // 512*3712 bf16
    unsigned short* WiB  = WuB + (size_t)LATENT * KPAD_U;         // 512*6144 bf16
    unsigned short* Uemb = WiB + (size_t)LATENT * KPAD_I;         // 8192*512 bf16
    unsigned short* P0   = Uemb + (size_t)BATCH * LATENT;         // 8192*512 bf16
    unsigned short* P1   = P0   + (size_t)BATCH * LATENT;         // 8192*512 bf16

    convert_w<<<dim3((KPAD_U + 255) / 256, LATENT), 256, 0, stream>>>(Wu, WuB, USER_DIM, KPAD_U);
    convert_w<<<dim3((KPAD_I + 255) / 256, LATENT), 256, 0, stream>>>(Wi, WiB, ITEM_DIM, KPAD_I);

    // 768 blocks = 3 per CU, all co-resident; 1 user + 2 item halves per CU.
    gemm_fused<<<768, 256, 0, stream>>>(x, WuB, bu, WiB, Uemb, P0, P1);

    rowdot<<<BATCH / 4, 256, 0, stream>>>(Uemb, P0, P1, bi, out);
}

// Round 6
// 222.617 us; speedup vs baseline: 1.6460x; 1.0652x over previous
//
#include <hip/hip_runtime.h>
#include <hip/hip_bf16.h>
#include <stdint.h>

#define USER_DIM 3706
#define ITEM_DIM 6040
#define LATENT   512
#define BATCH    8192
#define XCOLS    (USER_DIM + ITEM_DIM)   // 9746
#define KPAD_U   3712                     // 116 * 32
#define KPAD_I   6144                     // 192 * 32 (two halves of 96 steps)

typedef float f32x4 __attribute__((ext_vector_type(4)));
typedef short bf16x8 __attribute__((ext_vector_type(8)));

#define VMCNT(n) asm volatile("s_waitcnt vmcnt(" #n ")" ::: "memory")
#define LGKM0    asm volatile("s_waitcnt lgkmcnt(0)" ::: "memory")

static __device__ __forceinline__ unsigned short f2bf(float f) {
    union { float f; unsigned int u; } v; v.f = f;
    unsigned int u = v.u;
    u += 0x7fffu + ((u >> 16) & 1u);   // RNE (finite inputs)
    return (unsigned short)(u >> 16);
}
static __device__ __forceinline__ float bf2f(unsigned int b) {
    union { unsigned int u; float f; } v; v.u = b << 16; return v.f;
}
static __device__ __forceinline__ void gload16(const void* g, void* l) {
    __builtin_amdgcn_global_load_lds(
        (const __attribute__((address_space(1))) void*)g,
        (__attribute__((address_space(3))) void*)l, 16, 0, 0);
}
static __device__ __forceinline__ void BARRIER() {
    __builtin_amdgcn_sched_barrier(0);
    __builtin_amdgcn_s_barrier();
    __builtin_amdgcn_sched_barrier(0);
}

// ---- Kernel 1: weight fp32 -> bf16, zero-padded K ----
__global__ void convert_w(const float* __restrict__ W, unsigned short* __restrict__ Wb,
                          int K, int Kpad) {
    int c = blockIdx.x * blockDim.x + threadIdx.x;
    int r = blockIdx.y;
    if (c >= Kpad) return;
    unsigned short o = 0;
    if (c < K) o = f2bf(W[(size_t)r * K + c]);
    Wb[(size_t)r * Kpad + c] = o;
}

// ---- Kernel 2: fused towers. 128x128 tile, BK=32, all-bf16 LDS (32 KB),
// counted-vmcnt raw-barrier pipeline. A reg-staged (T14: load 1 iter ahead,
// write-side fp32->bf16 cvt). B via global_load_lds, source pre-swizzled.
// LDS layout (A and B identical): [64 segs][128B]; elem (row r, 16B-chunk g)
// at seg=r>>1, c8=((r&1)*4+g)^(seg&7). Linear writes, swizzle on source/read.
__global__ __launch_bounds__(256, 3) void gemm_fused(
    const float* __restrict__ X,
    const unsigned short* __restrict__ WuB, const float* __restrict__ bu,
    const unsigned short* __restrict__ WiB,
    unsigned short* __restrict__ Uemb,
    unsigned short* __restrict__ P0, unsigned short* __restrict__ P1)
{
    __shared__ unsigned short sA2[2][64 * 64];   // 2 x 8 KB bf16
    __shared__ unsigned short sB2[2][64 * 64];   // 2 x 8 KB bf16

    const int tid  = threadIdx.x;
    const int lane = tid & 63;
    const int wid  = tid >> 6;
    const int wm   = wid >> 1;
    const int wn   = wid & 1;

    // XCD-chunked bijective swizzle over 768 blocks (= 8 * 96).
    const int bid = blockIdx.x;
    const int swz = (bid & 7) * 96 + (bid >> 3);
    const int g4  = swz >> 2;          // 0..191
    const int nb  = swz & 3;

    // balanced tower interleave: 1 user (116 steps) : 2 item halves (96) per CU
    int mb, k0, nt, xoff, Kpad;
    const unsigned short* WB;
    bool isUser; int kh = 0;
    if (g4 % 3 == 0) {
        isUser = true;  mb = g4 / 3;
        k0 = 0; nt = KPAD_U / 32; xoff = 0; Kpad = KPAD_U; WB = WuB;
    } else {
        const int q = g4 - (g4 / 3 + 1);     // 0..127 bijective
        isUser = false; mb = q >> 1; kh = q & 1;
        k0 = kh * 96; nt = 96; xoff = USER_DIM; Kpad = KPAD_I; WB = WiB;
    }

    // ---- staging lane geometry (shared invariant: LDS[seg][c8] holds
    //      global(row = seg*2 + ((c8^(seg&7))>>2), kchunk = (c8^(seg&7))&3)) ----
    const int l8  = lane >> 3;                 // seg-in-issue / seg-in-op
    const int c8w = lane & 7;                  // LDS chunk this lane writes
    const int s8  = c8w ^ l8;                  // source-side swizzled chunk
    const int spr = s8 >> 2;                   // source row parity
    const int skc = (s8 & 3) * 8;              // source k-col (elements)

    float4 raf[2][2];                          // A regs, one tile deep

    auto ALOAD = [&](int t) {
        const int kb = t * 32;
        #pragma unroll
        for (int o = 0; o < 2; ++o) {
            const int sego = wid * 16 + o * 8 + l8;
            const int grow = mb * 128 + sego * 2 + spr;
            const int xc   = xoff + kb + skc;
            const float* s = X + (size_t)grow * XCOLS + xc;
            if (xc + 8 > XCOLS) s = X;         // item tail: junk x zero-B
            raf[o][0] = *(const float4*)s;
            raf[o][1] = *(const float4*)(s + 4);
        }
    };
    auto AWRITE = [&](int buf) {
        unsigned short* sA = sA2[buf];
        #pragma unroll
        for (int o = 0; o < 2; ++o) {
            const int sego = wid * 16 + o * 8 + l8;
            uint4 w;
            w.x = (unsigned)f2bf(raf[o][0].x) | ((unsigned)f2bf(raf[o][0].y) << 16);
            w.y = (unsigned)f2bf(raf[o][0].z) | ((unsigned)f2bf(raf[o][0].w) << 16);
            w.z = (unsigned)f2bf(raf[o][1].x) | ((unsigned)f2bf(raf[o][1].y) << 16);
            w.w = (unsigned)f2bf(raf[o][1].z) | ((unsigned)f2bf(raf[o][1].w) << 16);
            *(uint4*)(sA + sego * 64 + c8w * 8) = w;   // linear 128B per 8 lanes
        }
    };
    auto ISSUE_B = [&](int t, int buf) {
        const int kb = t * 32;
        unsigned short* sB = sB2[buf];
        #pragma unroll
        for (int j = 0; j < 2; ++j) {
            const int i  = wid * 2 + j;                // 0..7
            const int rt = (i * 8 + l8) * 2 + spr;     // tile row
            const unsigned short* s =
                WB + (size_t)(nb * 128 + rt) * Kpad + kb + skc;
            gload16(s, sB + i * 512);                  // linear 1KB dest
        }
    };

    // ---- fragment read geometry ----
    const int fr   = lane & 15;
    const int g    = lane >> 4;
    const int rc8  = ((((fr & 1) * 4) + g) ^ (fr >> 1)) * 8;   // short offset
    const int aro  = (wm * 32 + (fr >> 1)) * 64 + rc8;         // + mi*512
    const int bro  = (wn * 32 + (fr >> 1)) * 64 + rc8;         // + ni*512

    f32x4 acc[4][4];
    #pragma unroll
    for (int i = 0; i < 4; ++i)
        #pragma unroll
        for (int j = 0; j < 4; ++j) acc[i][j] = (f32x4)0.0f;

    auto COMPUTE = [&](int buf) {
        const unsigned short* sA = sA2[buf];
        const unsigned short* sB = sB2[buf];
        bf16x8 af[4], bfr[4];
        #pragma unroll
        for (int mi = 0; mi < 4; ++mi)
            af[mi] = *(const bf16x8*)(sA + aro + mi * 512);
        #pragma unroll
        for (int ni = 0; ni < 4; ++ni)
            bfr[ni] = *(const bf16x8*)(sB + bro + ni * 512);
        __builtin_amdgcn_s_setprio(1);
        #pragma unroll
        for (int mi = 0; mi < 4; ++mi)
            #pragma unroll
            for (int ni = 0; ni < 4; ++ni)
                acc[mi][ni] = __builtin_amdgcn_mfma_f32_16x16x32_bf16(
                    af[mi], bfr[ni], acc[mi][ni], 0, 0, 0);
        __builtin_amdgcn_s_setprio(0);
    };

    // ---- pipeline: 2 barriers/step, waits always counted mid-loop ----
    ALOAD(k0);                      // A(0) -> regs           [4 vm]
    ISSUE_B(k0, 0);                 // B(0) -> LDS0           [2 vm]
    AWRITE(0);                      // waits A(0) (auto vmcnt(2))
    ALOAD(k0 + 1);                  // A(1) -> regs
    LGKM0;
    VMCNT(4);                       // B(0) landed (A(1) stays in flight)
    BARRIER();                      // tile 0 ready
    ISSUE_B(k0 + 1, 1);             // B(1) in flight

    #pragma unroll 2
    for (int t = 0; t < nt - 2; ++t) {
        const int cur = t & 1;
        COMPUTE(cur);               // tile t
        AWRITE(cur ^ 1);            // A(t+1) regs (1 iter old) -> nxt
        ALOAD(k0 + t + 2);          // A(t+2) -> regs
        LGKM0;
        BARRIER();                  // cur reads done everywhere
        ISSUE_B(k0 + t + 2, cur);   // B(t+2) -> cur
        VMCNT(6);                   // retires B(t+1); A(t+2)+B(t+2) in flight
        BARRIER();                  // publish tile t+1
    }
    // t = nt-2 (cur = 0 since nt even)
    COMPUTE(0);
    AWRITE(1);                      // A(nt-1)
    LGKM0;
    BARRIER();
    VMCNT(0);                       // drain B(nt-1)
    BARRIER();
    COMPUTE(1);                     // tile nt-1

    // ---- epilogue ----
    const int cb = nb * 128 + wn * 64;
    const int rb = mb * 128 + wm * 64 + (lane >> 4) * 4;
    if (isUser) {
        #pragma unroll
        for (int ni = 0; ni < 4; ++ni) {
            const int col = cb + ni * 16 + fr;
            const float bv = bu[col];
            #pragma unroll
            for (int mi = 0; mi < 4; ++mi) {
                f32x4 v = acc[mi][ni];
                #pragma unroll
                for (int r = 0; r < 4; ++r) {
                    const int row = rb + mi * 16 + r;
                    Uemb[(size_t)row * LATENT + col] = f2bf(fmaxf(v[r] + bv, 0.0f));
                }
            }
        }
    } else {
        unsigned short* P = kh ? P1 : P0;
        #pragma unroll
        for (int ni = 0; ni < 4; ++ni) {
            const int col = cb + ni * 16 + fr;
            #pragma unroll
            for (int mi = 0; mi < 4; ++mi) {
                f32x4 v = acc[mi][ni];
                #pragma unroll
                for (int r = 0; r < 4; ++r) {
                    const int row = rb + mi * 16 + r;
                    P[(size_t)row * LATENT + col] = f2bf(v[r]);   // partial
                }
            }
        }
    }
}

// ---- Kernel 3: out[b] = sum_d U[b,d] * relu(P0[b,d] + P1[b,d] + bi[d]) ----
__global__ void rowdot(const unsigned short* __restrict__ U,
                       const unsigned short* __restrict__ P0,
                       const unsigned short* __restrict__ P1,
                       const float* __restrict__ bi,
                       float* __restrict__ out) {
    const int lane = threadIdx.x & 63;
    const int w    = threadIdx.x >> 6;
    const int row  = blockIdx.x * 4 + w;
    const size_t base = (size_t)row * LATENT + lane * 8;
    const uint4 uv = *(const uint4*)(U  + base);
    const uint4 p0 = *(const uint4*)(P0 + base);
    const uint4 p1 = *(const uint4*)(P1 + base);
    const float4 b0 = *(const float4*)(bi + lane * 8);
    const float4 b1 = *(const float4*)(bi + lane * 8 + 4);
    const float bb[8] = {b0.x, b0.y, b0.z, b0.w, b1.x, b1.y, b1.z, b1.w};
    const unsigned int* up = (const unsigned int*)&uv;
    const unsigned int* q0 = (const unsigned int*)&p0;
    const unsigned int* q1 = (const unsigned int*)&p1;
    float acc = 0.0f;
    #pragma unroll
    for (int q = 0; q < 4; ++q) {
        float ilo = fmaxf(bf2f(q0[q] & 0xffffu) + bf2f(q1[q] & 0xffffu) + bb[2 * q], 0.0f);
        float ihi = fmaxf(bf2f(q0[q] >> 16)     + bf2f(q1[q] >> 16)     + bb[2 * q + 1], 0.0f);
        acc += bf2f(up[q] & 0xffffu) * ilo;
        acc += bf2f(up[q] >> 16)     * ihi;
    }
    #pragma unroll
    for (int off = 32; off >= 1; off >>= 1)
        acc += __shfl_xor(acc, off, 64);
    if (lane == 0) out[row] = acc;
}

extern "C" void kernel_launch(void* const* d_in, const int* in_sizes, int n_in,
                              void* d_out, int out_size, void* d_ws, size_t ws_size,
                              hipStream_t stream) {
    const float* x  = (const float*)d_in[0];
    const float* Wu = (const float*)d_in[1];
    const float* bu = (const float*)d_in[2];
    const float* Wi = (const float*)d_in[3];
    const float* bi = (const float*)d_in[4];
    float* out = (float*)d_out;

    unsigned short* WuB  = (unsigned short*)d_ws;                 // 512*3712 bf16
    unsigned short* WiB  = WuB + (size_t)LATENT * KPAD_U;         // 512*6144 bf16
    unsigned short* Uemb = WiB + (size_t)LATENT * KPAD_I;         // 8192*512 bf16
    unsigned short* P0   = Uemb + (size_t)BATCH * LATENT;         // 8192*512 bf16
    unsigned short* P1   = P0   + (size_t)BATCH * LATENT;         // 8192*512 bf16

    convert_w<<<dim3((KPAD_U + 255) / 256, LATENT), 256, 0, stream>>>(Wu, WuB, USER_DIM, KPAD_U);
    convert_w<<<dim3((KPAD_I + 255) / 256, LATENT), 256, 0, stream>>>(Wi, WiB, ITEM_DIM, KPAD_I);

    // 768 blocks = 3 per CU co-resident; 1 user + 2 item halves per CU.
    gemm_fused<<<768, 256, 0, stream>>>(x, WuB, bu, WiB, Uemb, P0, P1);

    rowdot<<<BATCH / 4, 256, 0, stream>>>(Uemb, P0, P1, bi, out);
}